// Round 1
// baseline (298.912 us; speedup 1.0000x reference)
//
#include <hip/hip_runtime.h>

#define NT 8192      // tokens
#define CD 512       // C_K = C_V = 512
#define NH 8         // heads
#define KQV_LD 1536  // fused output width

using f32x4  = __attribute__((ext_vector_type(4))) float;
using bf16x8 = __attribute__((ext_vector_type(8))) __bf16;

__device__ __forceinline__ unsigned short f2bf(float x) {
    union { float f; unsigned u; } c; c.f = x;
    unsigned r = c.u + 0x7fffu + ((c.u >> 16) & 1u);
    return (unsigned short)(r >> 16);
}
__device__ __forceinline__ float bf2f(unsigned short b) {
    union { float f; unsigned u; } c; c.u = ((unsigned)b) << 16;
    return c.f;
}

// ---------------- prep kernels ----------------

// input fp32 [8192*512] -> bf16, 4 elems/thread
__global__ void cvt_input_k(const float4* __restrict__ in, unsigned short* __restrict__ out) {
    int i = blockIdx.x * 256 + threadIdx.x;   // 1048576 threads
    float4 v = in[i];
    out[i*4+0] = f2bf(v.x);
    out[i*4+1] = f2bf(v.y);
    out[i*4+2] = f2bf(v.z);
    out[i*4+3] = f2bf(v.w);
}

// Wt[c][k] = W_sec[k][c%512] bf16 (transposed, stacked k|q|v); biaskqv[1536]
__global__ void prep_w_k(const float* __restrict__ Wk, const float* __restrict__ Wq,
                         const float* __restrict__ Wv, const float* __restrict__ bk,
                         const float* __restrict__ bq, const float* __restrict__ bv,
                         unsigned short* __restrict__ Wt, float* __restrict__ biaskqv) {
    int idx = blockIdx.x * 256 + threadIdx.x;   // 1536*512
    int c = idx >> 9, k = idx & 511;
    int sec = c >> 9, cc = c & 511;
    const float* W = (sec == 0) ? Wk : ((sec == 1) ? Wq : Wv);
    Wt[idx] = f2bf(W[k * 512 + cc]);
    if (idx < 1536) {
        const float* b = (idx < 512) ? bk : ((idx < 1024) ? bq : bv);
        biaskqv[idx] = b[idx & 511];
    }
}

// ---------------- GEMM: C[M,N] = alpha * A[M,K] @ Bt[N,K]^T + bias[N] ----------------
// m97 structure: 128x128 tile, BK=32, 4 waves (2x2 of 64x64), global_load_lds w=16.
__global__ __launch_bounds__(256) void gemm_bt(
    const unsigned short* __restrict__ A, const unsigned short* __restrict__ Bt,
    float* __restrict__ C, const float* __restrict__ bias,
    int M, int N, int K, float alpha)
{
    __shared__ unsigned short sA[128 * 32];
    __shared__ unsigned short sB[128 * 32];
    const int tid  = threadIdx.x;
    const int wid  = tid >> 6;
    const int lane = tid & 63;
    const int col0 = blockIdx.x * 128;
    const int row0 = blockIdx.y * 128;
    const int wr = (wid >> 1) * 64;
    const int wc = (wid & 1) * 64;
    const int fr = lane & 15;
    const int fq = lane >> 4;
    const int srow = lane >> 2;        // row within 16-row staging segment
    const int scol = (lane & 3) * 8;   // bf16 col within 32

    f32x4 acc[4][4] = {};

    const int kTiles = K >> 5;
    for (int kt = 0; kt < kTiles; ++kt) {
        const int k0 = kt << 5;
        __syncthreads();  // previous compute done before overwriting LDS
        #pragma unroll
        for (int s = 0; s < 2; ++s) {
            const int seg = wid * 2 + s;  // 0..7, 16 rows each
            const unsigned short* gA = A + (size_t)(row0 + seg * 16 + srow) * K + k0 + scol;
            __builtin_amdgcn_global_load_lds(
                (const __attribute__((address_space(1))) void*)gA,
                (__attribute__((address_space(3))) void*)(sA + seg * 512), 16, 0, 0);
            const unsigned short* gB = Bt + (size_t)(col0 + seg * 16 + srow) * K + k0 + scol;
            __builtin_amdgcn_global_load_lds(
                (const __attribute__((address_space(1))) void*)gB,
                (__attribute__((address_space(3))) void*)(sB + seg * 512), 16, 0, 0);
        }
        __syncthreads();  // drains vmcnt before LDS reads

        bf16x8 av[4], bfrag[4];
        #pragma unroll
        for (int m = 0; m < 4; ++m)
            av[m] = *(const bf16x8*)(sA + (wr + m * 16 + fr) * 32 + fq * 8);
        #pragma unroll
        for (int n = 0; n < 4; ++n)
            bfrag[n] = *(const bf16x8*)(sB + (wc + n * 16 + fr) * 32 + fq * 8);
        #pragma unroll
        for (int m = 0; m < 4; ++m)
            #pragma unroll
            for (int n = 0; n < 4; ++n)
                acc[m][n] = __builtin_amdgcn_mfma_f32_16x16x32_bf16(av[m], bfrag[n], acc[m][n], 0, 0, 0);
    }

    // epilogue: C/D layout col=lane&15, row=(lane>>4)*4+reg
    #pragma unroll
    for (int n = 0; n < 4; ++n) {
        const int col = col0 + wc + n * 16 + fr;
        const float bval = bias ? bias[col] : 0.f;
        #pragma unroll
        for (int m = 0; m < 4; ++m) {
            #pragma unroll
            for (int r = 0; r < 4; ++r) {
                const int row = row0 + wr + m * 16 + fq * 4 + r;
                C[(size_t)row * N + col] = acc[m][n][r] * alpha + bval;
            }
        }
    }
}

// ---------------- key softmax (over tokens, per column) ----------------

__global__ void colmax_partial_k(const float* __restrict__ KQV, float* __restrict__ pmax) {
    int c = threadIdx.x;       // 512 threads
    int b = blockIdx.x;        // 64 blocks x 128 rows
    const float* p = KQV + (size_t)b * 128 * KQV_LD + c;
    float m = -1e30f;
    for (int r = 0; r < 128; ++r) m = fmaxf(m, p[(size_t)r * KQV_LD]);
    pmax[b * 512 + c] = m;
}
__global__ void colmax_final_k(const float* __restrict__ pmax, float* __restrict__ cmax) {
    int c = blockIdx.x * 256 + threadIdx.x;   // 512 total
    float m = -1e30f;
    for (int b = 0; b < 64; ++b) m = fmaxf(m, pmax[b * 512 + c]);
    cmax[c] = m;
}
__global__ void colsum_partial_k(const float* __restrict__ KQV, const float* __restrict__ cmax,
                                 float* __restrict__ psum) {
    int c = threadIdx.x;
    int b = blockIdx.x;
    const float* p = KQV + (size_t)b * 128 * KQV_LD + c;
    const float mx = cmax[c];
    float s = 0.f;
    for (int r = 0; r < 128; ++r) s += __expf(p[(size_t)r * KQV_LD] - mx);
    psum[b * 512 + c] = s;
}
__global__ void colsum_final_k(const float* __restrict__ psum, float* __restrict__ crcp) {
    int c = blockIdx.x * 256 + threadIdx.x;
    float s = 0.f;
    for (int b = 0; b < 64; ++b) s += psum[b * 512 + c];
    crcp[c] = 1.f / s;
}
__global__ void ksm_k(const float* __restrict__ KQV, const float* __restrict__ cmax,
                      const float* __restrict__ crcp, unsigned short* __restrict__ ksm) {
    int idx = blockIdx.x * 256 + threadIdx.x;   // 8192*512
    int n = idx >> 9, c = idx & 511;
    float x = __expf(KQV[(size_t)n * KQV_LD + c] - cmax[c]) * crcp[c];
    ksm[idx] = f2bf(x);
}

// ---------------- query softmax (over 64 channels) + v convert ----------------
__global__ void qsm_v_k(const float* __restrict__ KQV, unsigned short* __restrict__ qsm,
                        unsigned short* __restrict__ vbf) {
    int gw = (blockIdx.x * 256 + threadIdx.x) >> 6;   // wave id, 65536 total
    int lane = threadIdx.x & 63;
    int n = gw >> 3, h = gw & 7;
    float q = KQV[(size_t)n * KQV_LD + 512 + h * 64 + lane];
    float m = q;
    #pragma unroll
    for (int off = 32; off; off >>= 1) m = fmaxf(m, __shfl_xor(m, off));
    float e = __expf(q - m);
    float s = e;
    #pragma unroll
    for (int off = 32; off; off >>= 1) s += __shfl_xor(s, off);
    qsm[(size_t)gw * 64 + lane] = f2bf(e / s);
    vbf[(size_t)gw * 64 + lane] = f2bf(KQV[(size_t)n * KQV_LD + 1024 + h * 64 + lane]);
}

// ---------------- context = k_sm^T @ v per head (deterministic partials) ----------------
__global__ __launch_bounds__(256) void context_partial_k(
    const unsigned short* __restrict__ ksm, const unsigned short* __restrict__ vbf,
    float* __restrict__ pctx)
{
    const int ch = blockIdx.x;   // 32 chunks of 256 rows
    const int h  = blockIdx.y;   // 8 heads
    const int tid = threadIdx.x;
    const int i  = tid >> 2;          // k-channel 0..63
    const int j0 = (tid & 3) * 16;    // v-channel base
    __shared__ unsigned short kl[32][64];
    __shared__ unsigned short vl[32][64];
    float acc[16] = {};
    const int rowbase = ch * 256;
    for (int blk = 0; blk < 8; ++blk) {
        __syncthreads();
        for (int t = tid; t < 2048; t += 256) {
            int r = t >> 6, c = t & 63;
            int n = rowbase + blk * 32 + r;
            kl[r][c] = ksm[(size_t)n * 512 + h * 64 + c];
            vl[r][c] = vbf[(size_t)n * 512 + h * 64 + c];
        }
        __syncthreads();
        for (int r = 0; r < 32; ++r) {
            float kv = bf2f(kl[r][i]);
            #pragma unroll
            for (int jj = 0; jj < 16; ++jj)
                acc[jj] += kv * bf2f(vl[r][j0 + jj]);
        }
    }
    float* out = pctx + (size_t)(ch * 8 + h) * 4096;
    #pragma unroll
    for (int jj = 0; jj < 16; ++jj) out[i * 64 + j0 + jj] = acc[jj];
}
__global__ void context_reduce_k(const float* __restrict__ pctx, float* __restrict__ ctx) {
    int idx = blockIdx.x * 256 + threadIdx.x;   // 8*4096
    int h = idx >> 12, e = idx & 4095;
    float s = 0.f;
    for (int ch = 0; ch < 32; ++ch) s += pctx[(size_t)(ch * 8 + h) * 4096 + e];
    ctx[idx] = s;
}

// ---------------- Mt[o][h*64+k] = sum_j ctx[h][k][j] * Wr[h*64+j][o]  (bf16) ----------------
__global__ void mt_k(const float* __restrict__ ctx, const float* __restrict__ Wr,
                     unsigned short* __restrict__ Mt) {
    int idx = blockIdx.x * 256 + threadIdx.x;   // 512*512
    int o = idx >> 9, hk = idx & 511;
    int h = hk >> 6, k = hk & 63;
    float s = 0.f;
    for (int j = 0; j < 64; ++j)
        s += ctx[h * 4096 + k * 64 + j] * Wr[(size_t)(h * 64 + j) * 512 + o];
    Mt[(size_t)o * 512 + hk] = f2bf(s);
}

// ---------------- launch ----------------
extern "C" void kernel_launch(void* const* d_in, const int* in_sizes, int n_in,
                              void* d_out, int out_size, void* d_ws, size_t ws_size,
                              hipStream_t stream) {
    const float* input = (const float*)d_in[0];
    const float* Wk = (const float*)d_in[1];
    const float* bk = (const float*)d_in[2];
    const float* Wq = (const float*)d_in[3];
    const float* bq = (const float*)d_in[4];
    const float* Wv = (const float*)d_in[5];
    const float* bv = (const float*)d_in[6];
    const float* Wr = (const float*)d_in[7];
    const float* br = (const float*)d_in[8];

    char* ws = (char*)d_ws;
    unsigned short* inp_bf = (unsigned short*)ws;  ws += (size_t)NT * CD * 2;
    unsigned short* Wt     = (unsigned short*)ws;  ws += (size_t)1536 * 512 * 2;
    float* biaskqv         = (float*)ws;           ws += 1536 * 4;
    float* KQV             = (float*)ws;           ws += (size_t)NT * KQV_LD * 4;
    float* pmax            = (float*)ws;           ws += 64 * 512 * 4;
    float* cmax            = (float*)ws;           ws += 512 * 4;
    float* psum            = (float*)ws;           ws += 64 * 512 * 4;
    float* crcp            = (float*)ws;           ws += 512 * 4;
    unsigned short* ksm    = (unsigned short*)ws;  ws += (size_t)NT * CD * 2;
    unsigned short* qsm    = (unsigned short*)ws;  ws += (size_t)NT * CD * 2;
    unsigned short* vbf    = (unsigned short*)ws;  ws += (size_t)NT * CD * 2;
    float* pctx            = (float*)ws;           ws += (size_t)32 * 8 * 4096 * 4;
    float* ctx             = (float*)ws;           ws += (size_t)8 * 4096 * 4;
    unsigned short* Mt     = (unsigned short*)ws;  ws += (size_t)512 * 512 * 2;

    float* attn_out   = (float*)d_out;
    float* scores_out = (float*)d_out + (size_t)NT * CD;

    cvt_input_k<<<4096, 256, 0, stream>>>((const float4*)input, inp_bf);
    prep_w_k<<<3072, 256, 0, stream>>>(Wk, Wq, Wv, bk, bq, bv, Wt, biaskqv);

    // KQV = input @ [Wk|Wq|Wv] + bias
    gemm_bt<<<dim3(12, 64), 256, 0, stream>>>(inp_bf, Wt, KQV, biaskqv, NT, KQV_LD, CD, 1.0f);

    colmax_partial_k<<<64, 512, 0, stream>>>(KQV, pmax);
    colmax_final_k<<<2, 256, 0, stream>>>(pmax, cmax);
    colsum_partial_k<<<64, 512, 0, stream>>>(KQV, cmax, psum);
    colsum_final_k<<<2, 256, 0, stream>>>(psum, crcp);
    ksm_k<<<16384, 256, 0, stream>>>(KQV, cmax, crcp, ksm);
    qsm_v_k<<<16384, 256, 0, stream>>>(KQV, qsm, vbf);

    context_partial_k<<<dim3(32, 8), 256, 0, stream>>>(ksm, vbf, pctx);
    context_reduce_k<<<128, 256, 0, stream>>>(pctx, ctx);
    mt_k<<<1024, 256, 0, stream>>>(ctx, Wr, Mt);

    // attention = q_sm @ Mt^T + br  -> d_out[0 : 8192*512]
    gemm_bt<<<dim3(4, 64), 256, 0, stream>>>(qsm, Mt, attn_out, br, NT, CD, CD, 1.0f);
    // scores = q_sm @ k_sm^T / 8 -> d_out[8192*512 : ]
    gemm_bt<<<dim3(64, 64), 256, 0, stream>>>(qsm, ksm, scores_out, nullptr, NT, NT, CD, 0.125f);
}

// Round 2
// 279.393 us; speedup vs baseline: 1.0699x; 1.0699x over previous
//
#include <hip/hip_runtime.h>

#define NT 8192      // tokens
#define CD 512       // C_K = C_V = 512
#define NH 8         // heads
#define KQV_LD 1536  // fused output width
#define SC_N 8192

using f32x4  = __attribute__((ext_vector_type(4))) float;
using bf16x8 = __attribute__((ext_vector_type(8))) __bf16;

__device__ __forceinline__ unsigned short f2bf(float x) {
    union { float f; unsigned u; } c; c.f = x;
    unsigned r = c.u + 0x7fffu + ((c.u >> 16) & 1u);
    return (unsigned short)(r >> 16);
}
__device__ __forceinline__ float bf2f(unsigned short b) {
    union { float f; unsigned u; } c; c.u = ((unsigned)b) << 16;
    return c.f;
}

// ---------------- prep kernels ----------------

__global__ void cvt_input_k(const float4* __restrict__ in, unsigned short* __restrict__ out) {
    int i = blockIdx.x * 256 + threadIdx.x;   // 1048576 threads
    float4 v = in[i];
    out[i*4+0] = f2bf(v.x);
    out[i*4+1] = f2bf(v.y);
    out[i*4+2] = f2bf(v.z);
    out[i*4+3] = f2bf(v.w);
}

__global__ void prep_w_k(const float* __restrict__ Wk, const float* __restrict__ Wq,
                         const float* __restrict__ Wv, const float* __restrict__ bk,
                         const float* __restrict__ bq, const float* __restrict__ bv,
                         unsigned short* __restrict__ Wt, float* __restrict__ biaskqv) {
    int idx = blockIdx.x * 256 + threadIdx.x;   // 1536*512
    int c = idx >> 9, k = idx & 511;
    int sec = c >> 9, cc = c & 511;
    const float* W = (sec == 0) ? Wk : ((sec == 1) ? Wq : Wv);
    Wt[idx] = f2bf(W[k * 512 + cc]);
    if (idx < 1536) {
        const float* b = (idx < 512) ? bk : ((idx < 1024) ? bq : bv);
        biaskqv[idx] = b[idx & 511];
    }
}

// ---------------- m97-style GEMM: C[M,N] = alpha * A[M,K] @ Bt[N,K]^T + bias[N] ----------------
__global__ __launch_bounds__(256) void gemm_bt(
    const unsigned short* __restrict__ A, const unsigned short* __restrict__ Bt,
    float* __restrict__ C, const float* __restrict__ bias,
    int M, int N, int K, float alpha)
{
    __shared__ unsigned short sA[128 * 32];
    __shared__ unsigned short sB[128 * 32];
    const int tid  = threadIdx.x;
    const int wid  = tid >> 6;
    const int lane = tid & 63;
    const int col0 = blockIdx.x * 128;
    const int row0 = blockIdx.y * 128;
    const int wr = (wid >> 1) * 64;
    const int wc = (wid & 1) * 64;
    const int fr = lane & 15;
    const int fq = lane >> 4;
    const int srow = lane >> 2;
    const int scol = (lane & 3) * 8;

    f32x4 acc[4][4] = {};

    const int kTiles = K >> 5;
    for (int kt = 0; kt < kTiles; ++kt) {
        const int k0 = kt << 5;
        __syncthreads();
        #pragma unroll
        for (int s = 0; s < 2; ++s) {
            const int seg = wid * 2 + s;
            const unsigned short* gA = A + (size_t)(row0 + seg * 16 + srow) * K + k0 + scol;
            __builtin_amdgcn_global_load_lds(
                (const __attribute__((address_space(1))) void*)gA,
                (__attribute__((address_space(3))) void*)(sA + seg * 512), 16, 0, 0);
            const unsigned short* gB = Bt + (size_t)(col0 + seg * 16 + srow) * K + k0 + scol;
            __builtin_amdgcn_global_load_lds(
                (const __attribute__((address_space(1))) void*)gB,
                (__attribute__((address_space(3))) void*)(sB + seg * 512), 16, 0, 0);
        }
        __syncthreads();

        bf16x8 av[4], bfrag[4];
        #pragma unroll
        for (int m = 0; m < 4; ++m)
            av[m] = *(const bf16x8*)(sA + (wr + m * 16 + fr) * 32 + fq * 8);
        #pragma unroll
        for (int n = 0; n < 4; ++n)
            bfrag[n] = *(const bf16x8*)(sB + (wc + n * 16 + fr) * 32 + fq * 8);
        #pragma unroll
        for (int m = 0; m < 4; ++m)
            #pragma unroll
            for (int n = 0; n < 4; ++n)
                acc[m][n] = __builtin_amdgcn_mfma_f32_16x16x32_bf16(av[m], bfrag[n], acc[m][n], 0, 0, 0);
    }

    #pragma unroll
    for (int n = 0; n < 4; ++n) {
        const int col = col0 + wc + n * 16 + fr;
        const float bval = bias ? bias[col] : 0.f;
        #pragma unroll
        for (int m = 0; m < 4; ++m) {
            #pragma unroll
            for (int r = 0; r < 4; ++r) {
                const int row = row0 + wr + m * 16 + fq * 4 + r;
                C[(size_t)row * N + col] = acc[m][n][r] * alpha + bval;
            }
        }
    }
}

// ---------------- scores GEMM: 256x256 tile, BK=32, ring-4 LDS, counted vmcnt ----------------
// C[8192,8192] = 0.125 * A[8192,512] @ B[8192,512]^T   (A=qsm, B=ksm, bf16)
// LDS swizzle: physical 16B unit = logical ^ ((row&7)), applied identically on
// pre-swizzled global source (stage) and XOR'd ds_read address (read).
__global__ __launch_bounds__(512) void scores_gemm_k(
    const unsigned short* __restrict__ A, const unsigned short* __restrict__ B,
    float* __restrict__ C)
{
    __shared__ unsigned short lds[4][2][8192];   // [slot][A/B][256 rows * 32 cols] = 128 KiB
    const int tid  = threadIdx.x;
    const int wid  = tid >> 6;
    const int lane = tid & 63;
    const int fr = lane & 15;
    const int fq = lane >> 4;
    const int wm = wid >> 2;      // 0..1 -> 128-row half
    const int wn = wid & 3;       // 0..3 -> 64-col quarter

    // bijective XCD swizzle (1024 % 8 == 0) + GM=8 row-grouping for L2
    int g = blockIdx.x;
    g = (g & 7) * 128 + (g >> 3);
    const int by = (g & 7) + ((g >> 8) << 3);
    const int bx = (g >> 3) & 31;
    const int row0 = by * 256, col0 = bx * 256;

    // de-swizzled source coords for this thread's 2 staging units per operand
    int srow[2], scol8[2];
    #pragma unroll
    for (int l = 0; l < 2; ++l) {
        int i = l * 512 + tid;
        int b4 = (i >> 4) & 1, b3 = (i >> 3) & 1;
        int b2 = ((i >> 2) & 1) ^ b4;
        int b1 = ((i >> 1) & 1) ^ b3;
        int b0 = (i & 1) ^ b2;
        int U  = (i & ~7) | (b2 << 2) | (b1 << 1) | b0;
        srow[l]  = U >> 2;
        scol8[l] = (U & 3) * 8;
    }

    f32x4 acc[8][4] = {};

    auto STAGE = [&](int kt, int s) {
        const int k0 = kt * 32;
        #pragma unroll
        for (int l = 0; l < 2; ++l) {
            const unsigned short* gA = A + (size_t)(row0 + srow[l]) * 512 + k0 + scol8[l];
            __builtin_amdgcn_global_load_lds(
                (const __attribute__((address_space(1))) void*)gA,
                (__attribute__((address_space(3))) void*)(&lds[s][0][(l * 512 + wid * 64) * 8]), 16, 0, 0);
            const unsigned short* gB = B + (size_t)(col0 + srow[l]) * 512 + k0 + scol8[l];
            __builtin_amdgcn_global_load_lds(
                (const __attribute__((address_space(1))) void*)gB,
                (__attribute__((address_space(3))) void*)(&lds[s][1][(l * 512 + wid * 64) * 8]), 16, 0, 0);
        }
    };

    auto COMPUTE = [&](int s) {
        const char* sA = (const char*)&lds[s][0][0];
        const char* sB = (const char*)&lds[s][1][0];
        bf16x8 a[8], b[4];
        #pragma unroll
        for (int mf = 0; mf < 8; ++mf) {
            int row  = wm * 128 + mf * 16 + fr;
            int byte = (row * 64 + fq * 16) ^ ((row & 7) << 4);
            a[mf] = *(const bf16x8*)(sA + byte);
        }
        #pragma unroll
        for (int nf = 0; nf < 4; ++nf) {
            int row  = wn * 64 + nf * 16 + fr;
            int byte = (row * 64 + fq * 16) ^ ((row & 7) << 4);
            b[nf] = *(const bf16x8*)(sB + byte);
        }
        __builtin_amdgcn_s_setprio(1);
        #pragma unroll
        for (int mf = 0; mf < 8; ++mf)
            #pragma unroll
            for (int nf = 0; nf < 4; ++nf)
                acc[mf][nf] = __builtin_amdgcn_mfma_f32_16x16x32_bf16(a[mf], b[nf], acc[mf][nf], 0, 0, 0);
        __builtin_amdgcn_s_setprio(0);
    };

    // prologue: stage tiles 0,1,2 (12 loads/thread); tile 0 resident after vmcnt(8)
    STAGE(0, 0); STAGE(1, 1); STAGE(2, 2);
    asm volatile("s_waitcnt vmcnt(8)" ::: "memory");
    __builtin_amdgcn_s_barrier();

    for (int t = 0; t < 13; ++t) {           // 16 K-tiles total (K=512, BK=32)
        STAGE(t + 3, (t + 3) & 3);
        COMPUTE(t & 3);
        asm volatile("s_waitcnt vmcnt(8)" ::: "memory");  // tile t+1 landed (t+2,t+3 in flight)
        __builtin_amdgcn_s_barrier();
    }
    COMPUTE(1);                              // t=13
    asm volatile("s_waitcnt vmcnt(4)" ::: "memory");      // tile 14 landed
    __builtin_amdgcn_s_barrier();
    COMPUTE(2);                              // t=14
    asm volatile("s_waitcnt vmcnt(0)" ::: "memory");      // tile 15 landed
    __builtin_amdgcn_s_barrier();
    COMPUTE(3);                              // t=15

    #pragma unroll
    for (int mf = 0; mf < 8; ++mf) {
        const int rowb = row0 + wm * 128 + mf * 16 + fq * 4;
        #pragma unroll
        for (int nf = 0; nf < 4; ++nf) {
            const int col = col0 + wn * 64 + nf * 16 + fr;
            #pragma unroll
            for (int r = 0; r < 4; ++r)
                C[(size_t)(rowb + r) * SC_N + col] = acc[mf][nf][r] * 0.125f;
        }
    }
}

// ---------------- key softmax (over tokens, per column), fused online max+sum ----------------

__global__ void colms_partial_k(const float* __restrict__ KQV,
                                float* __restrict__ pmax, float* __restrict__ psum) {
    int c = threadIdx.x;       // 512 threads
    int b = blockIdx.x;        // 64 blocks x 128 rows
    const float* p = KQV + (size_t)b * 128 * KQV_LD + c;
    float m = -1e30f, s = 0.f;
    for (int r = 0; r < 128; ++r) {
        float x = p[(size_t)r * KQV_LD];
        if (x > m) { s = s * __expf(m - x) + 1.f; m = x; }
        else s += __expf(x - m);
    }
    pmax[b * 512 + c] = m;
    psum[b * 512 + c] = s;
}
__global__ void colms_final_k(const float* __restrict__ pmax, const float* __restrict__ psum,
                              float* __restrict__ cmax, float* __restrict__ crcp) {
    int c = blockIdx.x * 256 + threadIdx.x;   // 512 total
    float m = -1e30f;
    for (int b = 0; b < 64; ++b) m = fmaxf(m, pmax[b * 512 + c]);
    float s = 0.f;
    for (int b = 0; b < 64; ++b) s += psum[b * 512 + c] * __expf(pmax[b * 512 + c] - m);
    cmax[c] = m;
    crcp[c] = 1.f / s;
}
__global__ void ksm_k(const float* __restrict__ KQV, const float* __restrict__ cmax,
                      const float* __restrict__ crcp, unsigned short* __restrict__ ksm) {
    int idx = blockIdx.x * 256 + threadIdx.x;   // 8192*512
    int n = idx >> 9, c = idx & 511;
    float x = __expf(KQV[(size_t)n * KQV_LD + c] - cmax[c]) * crcp[c];
    ksm[idx] = f2bf(x);
}

// ---------------- query softmax (over 64 channels) + v convert ----------------
__global__ void qsm_v_k(const float* __restrict__ KQV, unsigned short* __restrict__ qsm,
                        unsigned short* __restrict__ vbf) {
    int gw = (blockIdx.x * 256 + threadIdx.x) >> 6;   // wave id, 65536 total
    int lane = threadIdx.x & 63;
    int n = gw >> 3, h = gw & 7;
    float q = KQV[(size_t)n * KQV_LD + 512 + h * 64 + lane];
    float m = q;
    #pragma unroll
    for (int off = 32; off; off >>= 1) m = fmaxf(m, __shfl_xor(m, off));
    float e = __expf(q - m);
    float s = e;
    #pragma unroll
    for (int off = 32; off; off >>= 1) s += __shfl_xor(s, off);
    qsm[(size_t)gw * 64 + lane] = f2bf(e / s);
    vbf[(size_t)gw * 64 + lane] = f2bf(KQV[(size_t)n * KQV_LD + 1024 + h * 64 + lane]);
}

// ---------------- context = k_sm^T @ v per head via MFMA on LDS-transposed tiles ----------------
// Per block: chunk of 256 tokens, one head. Wave w owns 64 tokens; MFMA contracts
// over tokens (K-dim), M=k-channel, N=v-channel. Transposed LDS tiles are
// XOR-swizzled (unit ^= row&7) -> conflict-free writes, 2-way reads.
__global__ __launch_bounds__(256) void context_partial_k(
    const unsigned short* __restrict__ ksm, const unsigned short* __restrict__ vbf,
    float* __restrict__ pctx)
{
    const int ch = blockIdx.x;   // 32 chunks x 256 rows
    const int h  = blockIdx.y;   // 8 heads
    const int tid = threadIdx.x, w = tid >> 6, lane = tid & 63;
    const int fr = lane & 15, fq = lane >> 4;
    __shared__ unsigned short tr[4][2][4096];   // [wave][k/v][64 kchan * 64 tok] = 64 KiB
    char* kt = (char*)&tr[w][0][0];
    char* vt = (char*)&tr[w][1][0];
    const int nbase = ch * 256 + w * 64;

    #pragma unroll
    for (int j = 0; j < 8; ++j) {
        bf16x8 kv = *(const bf16x8*)(ksm + (size_t)(nbase + lane) * 512 + h * 64 + j * 8);
        bf16x8 vv = *(const bf16x8*)(vbf + (size_t)(nbase + lane) * 512 + h * 64 + j * 8);
        #pragma unroll
        for (int e = 0; e < 8; ++e) {
            int k = j * 8 + e;
            int byte = (k * 128 + lane * 2) ^ (e << 4);   // k&7 == e
            *(unsigned short*)(kt + byte) = ((const unsigned short*)&kv)[e];
            *(unsigned short*)(vt + byte) = ((const unsigned short*)&vv)[e];
        }
    }
    asm volatile("s_waitcnt lgkmcnt(0)" ::: "memory");
    __builtin_amdgcn_sched_barrier(0);

    f32x4 acc[4][4] = {};
    #pragma unroll
    for (int ks = 0; ks < 2; ++ks) {
        bf16x8 a[4], b[4];
        #pragma unroll
        for (int mf = 0; mf < 4; ++mf) {
            int row  = mf * 16 + fr;
            int byte = (row * 128 + (ks * 4 + fq) * 16) ^ ((row & 7) << 4);
            a[mf] = *(const bf16x8*)(kt + byte);
            b[mf] = *(const bf16x8*)(vt + byte);
        }
        #pragma unroll
        for (int mf = 0; mf < 4; ++mf)
            #pragma unroll
            for (int nf = 0; nf < 4; ++nf)
                acc[mf][nf] = __builtin_amdgcn_mfma_f32_16x16x32_bf16(a[mf], b[nf], acc[mf][nf], 0, 0, 0);
    }

    float* out = pctx + (size_t)((ch * 4 + w) * 8 + h) * 4096;
    #pragma unroll
    for (int mf = 0; mf < 4; ++mf)
        #pragma unroll
        for (int nf = 0; nf < 4; ++nf)
            #pragma unroll
            for (int r = 0; r < 4; ++r)
                out[(mf * 16 + fq * 4 + r) * 64 + nf * 16 + fr] = acc[mf][nf][r];
}
__global__ void context_reduce_k(const float* __restrict__ pctx, float* __restrict__ ctx) {
    int idx = blockIdx.x * 256 + threadIdx.x;   // 8*4096 = 32768
    int h = idx >> 12, e = idx & 4095;
    float s = 0.f;
    for (int p = 0; p < 128; ++p) s += pctx[(size_t)(p * 8 + h) * 4096 + e];
    ctx[idx] = s;
}

// ---------------- Mt[o][h*64+k] = sum_j ctx[h][k][j] * Wr[h*64+j][o]  (bf16) ----------------
__global__ void mt_k(const float* __restrict__ ctx, const float* __restrict__ Wr,
                     unsigned short* __restrict__ Mt) {
    int idx = blockIdx.x * 256 + threadIdx.x;   // 512*512
    int o = idx >> 9, hk = idx & 511;
    int h = hk >> 6, k = hk & 63;
    float s = 0.f;
    for (int j = 0; j < 64; ++j)
        s += ctx[h * 4096 + k * 64 + j] * Wr[(size_t)(h * 64 + j) * 512 + o];
    Mt[(size_t)o * 512 + hk] = f2bf(s);
}

// ---------------- launch ----------------
extern "C" void kernel_launch(void* const* d_in, const int* in_sizes, int n_in,
                              void* d_out, int out_size, void* d_ws, size_t ws_size,
                              hipStream_t stream) {
    const float* input = (const float*)d_in[0];
    const float* Wk = (const float*)d_in[1];
    const float* bk = (const float*)d_in[2];
    const float* Wq = (const float*)d_in[3];
    const float* bq = (const float*)d_in[4];
    const float* Wv = (const float*)d_in[5];
    const float* bv = (const float*)d_in[6];
    const float* Wr = (const float*)d_in[7];
    const float* br = (const float*)d_in[8];

    char* ws = (char*)d_ws;
    unsigned short* inp_bf = (unsigned short*)ws;  ws += (size_t)NT * CD * 2;
    unsigned short* Wt     = (unsigned short*)ws;  ws += (size_t)1536 * 512 * 2;
    float* biaskqv         = (float*)ws;           ws += 1536 * 4;
    float* KQV             = (float*)ws;           ws += (size_t)NT * KQV_LD * 4;
    float* pmax            = (float*)ws;           ws += 64 * 512 * 4;
    float* cmax            = (float*)ws;           ws += 512 * 4;
    float* psum            = (float*)ws;           ws += 64 * 512 * 4;
    float* crcp            = (float*)ws;           ws += 512 * 4;
    unsigned short* ksm    = (unsigned short*)ws;  ws += (size_t)NT * CD * 2;
    unsigned short* qsm    = (unsigned short*)ws;  ws += (size_t)NT * CD * 2;
    unsigned short* vbf    = (unsigned short*)ws;  ws += (size_t)NT * CD * 2;
    float* ctx             = (float*)ws;           ws += (size_t)8 * 4096 * 4;
    unsigned short* Mt     = (unsigned short*)ws;  ws += (size_t)512 * 512 * 2;
    // pctx (16.8 MB) aliases KQV (50.3 MB): KQV is dead once ksm/qsm/vbf exist.
    float* pctx = KQV;

    float* attn_out   = (float*)d_out;
    float* scores_out = (float*)d_out + (size_t)NT * CD;

    cvt_input_k<<<4096, 256, 0, stream>>>((const float4*)input, inp_bf);
    prep_w_k<<<3072, 256, 0, stream>>>(Wk, Wq, Wv, bk, bq, bv, Wt, biaskqv);

    gemm_bt<<<dim3(12, 64), 256, 0, stream>>>(inp_bf, Wt, KQV, biaskqv, NT, KQV_LD, CD, 1.0f);

    colms_partial_k<<<64, 512, 0, stream>>>(KQV, pmax, psum);
    colms_final_k<<<2, 256, 0, stream>>>(pmax, psum, cmax, crcp);
    ksm_k<<<16384, 256, 0, stream>>>(KQV, cmax, crcp, ksm);
    qsm_v_k<<<16384, 256, 0, stream>>>(KQV, qsm, vbf);

    context_partial_k<<<dim3(32, 8), 256, 0, stream>>>(ksm, vbf, pctx);
    context_reduce_k<<<128, 256, 0, stream>>>(pctx, ctx);
    mt_k<<<1024, 256, 0, stream>>>(ctx, Wr, Mt);

    gemm_bt<<<dim3(4, 64), 256, 0, stream>>>(qsm, Mt, attn_out, br, NT, CD, CD, 1.0f);
    scores_gemm_k<<<1024, 512, 0, stream>>>(qsm, ksm, scores_out);
}

// Round 3
// 271.265 us; speedup vs baseline: 1.1019x; 1.0300x over previous
//
#include <hip/hip_runtime.h>

#define NT 8192      // tokens
#define CD 512       // C_K = C_V = 512
#define NH 8         // heads
#define KQV_LD 1536  // fused output width
#define SC_N 8192

using f32x4  = __attribute__((ext_vector_type(4))) float;
using bf16x8 = __attribute__((ext_vector_type(8))) __bf16;

__device__ __forceinline__ unsigned short f2bf(float x) {
    union { float f; unsigned u; } c; c.f = x;
    unsigned r = c.u + 0x7fffu + ((c.u >> 16) & 1u);
    return (unsigned short)(r >> 16);
}
__device__ __forceinline__ float bf2f(unsigned short b) {
    union { float f; unsigned u; } c; c.u = ((unsigned)b) << 16;
    return c.f;
}

// ---------------- prep kernels ----------------

__global__ void cvt_input_k(const float4* __restrict__ in, unsigned short* __restrict__ out) {
    int i = blockIdx.x * 256 + threadIdx.x;   // 1048576 threads
    float4 v = in[i];
    out[i*4+0] = f2bf(v.x);
    out[i*4+1] = f2bf(v.y);
    out[i*4+2] = f2bf(v.z);
    out[i*4+3] = f2bf(v.w);
}

__global__ void prep_w_k(const float* __restrict__ Wk, const float* __restrict__ Wq,
                         const float* __restrict__ Wv, const float* __restrict__ bk,
                         const float* __restrict__ bq, const float* __restrict__ bv,
                         unsigned short* __restrict__ Wt, float* __restrict__ biaskqv) {
    int idx = blockIdx.x * 256 + threadIdx.x;   // 1536*512
    int c = idx >> 9, k = idx & 511;
    int sec = c >> 9, cc = c & 511;
    const float* W = (sec == 0) ? Wk : ((sec == 1) ? Wq : Wv);
    Wt[idx] = f2bf(W[k * 512 + cc]);
    if (idx < 1536) {
        const float* b = (idx < 512) ? bk : ((idx < 1024) ? bq : bv);
        biaskqv[idx] = b[idx & 511];
    }
}

// ---------------- m97-style GEMM: C[M,N] = alpha * A[M,K] @ Bt[N,K]^T + bias[N] ----------------
__global__ __launch_bounds__(256) void gemm_bt(
    const unsigned short* __restrict__ A, const unsigned short* __restrict__ Bt,
    float* __restrict__ C, const float* __restrict__ bias,
    int M, int N, int K, float alpha)
{
    __shared__ unsigned short sA[128 * 32];
    __shared__ unsigned short sB[128 * 32];
    const int tid  = threadIdx.x;
    const int wid  = tid >> 6;
    const int lane = tid & 63;
    const int col0 = blockIdx.x * 128;
    const int row0 = blockIdx.y * 128;
    const int wr = (wid >> 1) * 64;
    const int wc = (wid & 1) * 64;
    const int fr = lane & 15;
    const int fq = lane >> 4;
    const int srow = lane >> 2;
    const int scol = (lane & 3) * 8;

    f32x4 acc[4][4] = {};

    const int kTiles = K >> 5;
    for (int kt = 0; kt < kTiles; ++kt) {
        const int k0 = kt << 5;
        __syncthreads();
        #pragma unroll
        for (int s = 0; s < 2; ++s) {
            const int seg = wid * 2 + s;
            const unsigned short* gA = A + (size_t)(row0 + seg * 16 + srow) * K + k0 + scol;
            __builtin_amdgcn_global_load_lds(
                (const __attribute__((address_space(1))) void*)gA,
                (__attribute__((address_space(3))) void*)(sA + seg * 512), 16, 0, 0);
            const unsigned short* gB = Bt + (size_t)(col0 + seg * 16 + srow) * K + k0 + scol;
            __builtin_amdgcn_global_load_lds(
                (const __attribute__((address_space(1))) void*)gB,
                (__attribute__((address_space(3))) void*)(sB + seg * 512), 16, 0, 0);
        }
        __syncthreads();

        bf16x8 av[4], bfrag[4];
        #pragma unroll
        for (int m = 0; m < 4; ++m)
            av[m] = *(const bf16x8*)(sA + (wr + m * 16 + fr) * 32 + fq * 8);
        #pragma unroll
        for (int n = 0; n < 4; ++n)
            bfrag[n] = *(const bf16x8*)(sB + (wc + n * 16 + fr) * 32 + fq * 8);
        #pragma unroll
        for (int m = 0; m < 4; ++m)
            #pragma unroll
            for (int n = 0; n < 4; ++n)
                acc[m][n] = __builtin_amdgcn_mfma_f32_16x16x32_bf16(av[m], bfrag[n], acc[m][n], 0, 0, 0);
    }

    #pragma unroll
    for (int n = 0; n < 4; ++n) {
        const int col = col0 + wc + n * 16 + fr;
        const float bval = bias ? bias[col] : 0.f;
        #pragma unroll
        for (int m = 0; m < 4; ++m) {
            #pragma unroll
            for (int r = 0; r < 4; ++r) {
                const int row = row0 + wr + m * 16 + fq * 4 + r;
                C[(size_t)row * N + col] = acc[m][n][r] * alpha + bval;
            }
        }
    }
}

// ---------------- scores GEMM: 256x256 tile, BK=32, ring-4 LDS, counted vmcnt ----------------
// C[8192,8192] = 0.125 * A[8192,512] @ B[8192,512]^T
// T3 pipeline: A-fragments for tile t+1 are ds_read right after the barrier that
// proves tile t+1 resident, consumed one phase later -> LDS drain overlaps MFMA.
// B-fragments just-in-time (saves 32 VGPR). Two named reg sets (aX/aY), unroll-2.
__global__ __launch_bounds__(512) void scores_gemm_k(
    const unsigned short* __restrict__ A, const unsigned short* __restrict__ B,
    float* __restrict__ C)
{
    __shared__ unsigned short lds[4][2][8192];   // [slot][A/B][256 rows * 32 cols] = 128 KiB
    const int tid  = threadIdx.x;
    const int wid  = tid >> 6;
    const int lane = tid & 63;
    const int fr = lane & 15;
    const int fq = lane >> 4;
    const int wm = wid >> 2;      // 0..1 -> 128-row half
    const int wn = wid & 3;       // 0..3 -> 64-col quarter

    // bijective XCD swizzle (1024 % 8 == 0) + GM=8 row-grouping for L2
    int g = blockIdx.x;
    g = (g & 7) * 128 + (g >> 3);
    const int by = (g & 7) + ((g >> 8) << 3);
    const int bx = (g >> 3) & 31;
    const int row0 = by * 256, col0 = bx * 256;

    // de-swizzled source coords for this thread's 2 staging units per operand
    int srow[2], scol8[2];
    #pragma unroll
    for (int l = 0; l < 2; ++l) {
        int i = l * 512 + tid;
        int b4 = (i >> 4) & 1, b3 = (i >> 3) & 1;
        int b2 = ((i >> 2) & 1) ^ b4;
        int b1 = ((i >> 1) & 1) ^ b3;
        int b0 = (i & 1) ^ b2;
        int U  = (i & ~7) | (b2 << 2) | (b1 << 1) | b0;
        srow[l]  = U >> 2;
        scol8[l] = (U & 3) * 8;
    }

    // swizzled LDS byte offsets for this thread's fragments
    int offA[8], offB[4];
    #pragma unroll
    for (int mf = 0; mf < 8; ++mf) {
        int row = wm * 128 + mf * 16 + fr;
        offA[mf] = ((row * 4 + fq) ^ (row & 7)) << 4;
    }
    #pragma unroll
    for (int nf = 0; nf < 4; ++nf) {
        int row = wn * 64 + nf * 16 + fr;
        offB[nf] = ((row * 4 + fq) ^ (row & 7)) << 4;
    }

    f32x4 acc[8][4] = {};
    bf16x8 aX[8], aY[8];

    auto STAGE = [&](int kt, int s) {
        const int k0 = kt * 32;
        #pragma unroll
        for (int l = 0; l < 2; ++l) {
            const unsigned short* gA = A + (size_t)(row0 + srow[l]) * 512 + k0 + scol8[l];
            __builtin_amdgcn_global_load_lds(
                (const __attribute__((address_space(1))) void*)gA,
                (__attribute__((address_space(3))) void*)(&lds[s][0][(l * 512 + wid * 64) * 8]), 16, 0, 0);
            const unsigned short* gB = B + (size_t)(col0 + srow[l]) * 512 + k0 + scol8[l];
            __builtin_amdgcn_global_load_lds(
                (const __attribute__((address_space(1))) void*)gB,
                (__attribute__((address_space(3))) void*)(&lds[s][1][(l * 512 + wid * 64) * 8]), 16, 0, 0);
        }
    };

    auto LDA = [&](int s, bf16x8* a) {
        const char* sA = (const char*)&lds[s][0][0];
        #pragma unroll
        for (int mf = 0; mf < 8; ++mf) a[mf] = *(const bf16x8*)(sA + offA[mf]);
    };

    auto MFMAS = [&](int s, const bf16x8* a) {
        const char* sB = (const char*)&lds[s][1][0];
        bf16x8 b[4];
        #pragma unroll
        for (int nf = 0; nf < 4; ++nf) b[nf] = *(const bf16x8*)(sB + offB[nf]);
        __builtin_amdgcn_s_setprio(1);
        #pragma unroll
        for (int nf = 0; nf < 4; ++nf)
            #pragma unroll
            for (int mf = 0; mf < 8; ++mf)
                acc[mf][nf] = __builtin_amdgcn_mfma_f32_16x16x32_bf16(a[mf], b[nf], acc[mf][nf], 0, 0, 0);
        __builtin_amdgcn_s_setprio(0);
    };

    // prologue: stage tiles 0,1,2; tile 0 resident after vmcnt(8); load its A-frags
    STAGE(0, 0); STAGE(1, 1); STAGE(2, 2);
    asm volatile("s_waitcnt vmcnt(8)" ::: "memory");
    __builtin_amdgcn_s_barrier();
    asm volatile("" ::: "memory");
    LDA(0, aX);

    // main loop: tiles 0..11 (pairs), staging runs 3 tiles ahead
    for (int t = 0; t < 12; t += 2) {
        STAGE(t + 3, (t + 3) & 3);
        MFMAS(t & 3, aX);
        asm volatile("s_waitcnt vmcnt(8)" ::: "memory");   // tile t+1 landed
        __builtin_amdgcn_s_barrier();
        asm volatile("" ::: "memory");
        LDA((t + 1) & 3, aY);

        STAGE(t + 4, (t + 4) & 3);
        MFMAS((t + 1) & 3, aY);
        asm volatile("s_waitcnt vmcnt(8)" ::: "memory");   // tile t+2 landed
        __builtin_amdgcn_s_barrier();
        asm volatile("" ::: "memory");
        LDA((t + 2) & 3, aX);
    }
    // tail: tiles 12..15
    STAGE(15, 3);
    MFMAS(0, aX);                                          // tile 12
    asm volatile("s_waitcnt vmcnt(8)" ::: "memory");       // tile 13 landed
    __builtin_amdgcn_s_barrier();
    asm volatile("" ::: "memory");
    LDA(1, aY);
    MFMAS(1, aY);                                          // tile 13
    asm volatile("s_waitcnt vmcnt(4)" ::: "memory");       // tile 14 landed
    __builtin_amdgcn_s_barrier();
    asm volatile("" ::: "memory");
    LDA(2, aX);
    MFMAS(2, aX);                                          // tile 14
    asm volatile("s_waitcnt vmcnt(0)" ::: "memory");       // tile 15 landed
    __builtin_amdgcn_s_barrier();
    asm volatile("" ::: "memory");
    LDA(3, aY);
    MFMAS(3, aY);                                          // tile 15

    #pragma unroll
    for (int mf = 0; mf < 8; ++mf) {
        const int rowb = row0 + wm * 128 + mf * 16 + fq * 4;
        #pragma unroll
        for (int nf = 0; nf < 4; ++nf) {
            const int col = col0 + wn * 64 + nf * 16 + fr;
            #pragma unroll
            for (int r = 0; r < 4; ++r)
                C[(size_t)(rowb + r) * SC_N + col] = acc[mf][nf][r] * 0.125f;
        }
    }
}

// ---------------- key softmax (over tokens, per column), fused online max+sum ----------------

__global__ void colms_partial_k(const float* __restrict__ KQV,
                                float* __restrict__ pmax, float* __restrict__ psum) {
    int c = threadIdx.x;       // 512 threads
    int b = blockIdx.x;        // 64 blocks x 128 rows
    const float* p = KQV + (size_t)b * 128 * KQV_LD + c;
    float m = -1e30f, s = 0.f;
    for (int r = 0; r < 128; ++r) {
        float x = p[(size_t)r * KQV_LD];
        if (x > m) { s = s * __expf(m - x) + 1.f; m = x; }
        else s += __expf(x - m);
    }
    pmax[b * 512 + c] = m;
    psum[b * 512 + c] = s;
}
__global__ void colms_final_k(const float* __restrict__ pmax, const float* __restrict__ psum,
                              float* __restrict__ cmax, float* __restrict__ crcp) {
    int c = blockIdx.x * 256 + threadIdx.x;   // 512 total
    float m = -1e30f;
    for (int b = 0; b < 64; ++b) m = fmaxf(m, pmax[b * 512 + c]);
    float s = 0.f;
    for (int b = 0; b < 64; ++b) s += psum[b * 512 + c] * __expf(pmax[b * 512 + c] - m);
    cmax[c] = m;
    crcp[c] = 1.f / s;
}
__global__ void ksm_k(const float* __restrict__ KQV, const float* __restrict__ cmax,
                      const float* __restrict__ crcp, unsigned short* __restrict__ ksm) {
    int idx = blockIdx.x * 256 + threadIdx.x;   // 8192*512
    int n = idx >> 9, c = idx & 511;
    float x = __expf(KQV[(size_t)n * KQV_LD + c] - cmax[c]) * crcp[c];
    ksm[idx] = f2bf(x);
}

// ---------------- query softmax (over 64 channels) + v convert ----------------
__global__ void qsm_v_k(const float* __restrict__ KQV, unsigned short* __restrict__ qsm,
                        unsigned short* __restrict__ vbf) {
    int gw = (blockIdx.x * 256 + threadIdx.x) >> 6;   // wave id, 65536 total
    int lane = threadIdx.x & 63;
    int n = gw >> 3, h = gw & 7;
    float q = KQV[(size_t)n * KQV_LD + 512 + h * 64 + lane];
    float m = q;
    #pragma unroll
    for (int off = 32; off; off >>= 1) m = fmaxf(m, __shfl_xor(m, off));
    float e = __expf(q - m);
    float s = e;
    #pragma unroll
    for (int off = 32; off; off >>= 1) s += __shfl_xor(s, off);
    qsm[(size_t)gw * 64 + lane] = f2bf(e / s);
    vbf[(size_t)gw * 64 + lane] = f2bf(KQV[(size_t)n * KQV_LD + 1024 + h * 64 + lane]);
}

// ---------------- context = k_sm^T @ v per head via MFMA on LDS-transposed tiles ----------------
__global__ __launch_bounds__(256) void context_partial_k(
    const unsigned short* __restrict__ ksm, const unsigned short* __restrict__ vbf,
    float* __restrict__ pctx)
{
    const int ch = blockIdx.x;   // 32 chunks x 256 rows
    const int h  = blockIdx.y;   // 8 heads
    const int tid = threadIdx.x, w = tid >> 6, lane = tid & 63;
    const int fr = lane & 15, fq = lane >> 4;
    __shared__ unsigned short tr[4][2][4096];   // [wave][k/v][64 kchan * 64 tok] = 64 KiB
    char* kt = (char*)&tr[w][0][0];
    char* vt = (char*)&tr[w][1][0];
    const int nbase = ch * 256 + w * 64;

    #pragma unroll
    for (int j = 0; j < 8; ++j) {
        bf16x8 kv = *(const bf16x8*)(ksm + (size_t)(nbase + lane) * 512 + h * 64 + j * 8);
        bf16x8 vv = *(const bf16x8*)(vbf + (size_t)(nbase + lane) * 512 + h * 64 + j * 8);
        #pragma unroll
        for (int e = 0; e < 8; ++e) {
            int k = j * 8 + e;
            int byte = (k * 128 + lane * 2) ^ (e << 4);   // k&7 == e
            *(unsigned short*)(kt + byte) = ((const unsigned short*)&kv)[e];
            *(unsigned short*)(vt + byte) = ((const unsigned short*)&vv)[e];
        }
    }
    asm volatile("s_waitcnt lgkmcnt(0)" ::: "memory");
    __builtin_amdgcn_sched_barrier(0);

    f32x4 acc[4][4] = {};
    #pragma unroll
    for (int ks = 0; ks < 2; ++ks) {
        bf16x8 a[4], b[4];
        #pragma unroll
        for (int mf = 0; mf < 4; ++mf) {
            int row  = mf * 16 + fr;
            int byte = (row * 128 + (ks * 4 + fq) * 16) ^ ((row & 7) << 4);
            a[mf] = *(const bf16x8*)(kt + byte);
            b[mf] = *(const bf16x8*)(vt + byte);
        }
        #pragma unroll
        for (int mf = 0; mf < 4; ++mf)
            #pragma unroll
            for (int nf = 0; nf < 4; ++nf)
                acc[mf][nf] = __builtin_amdgcn_mfma_f32_16x16x32_bf16(a[mf], b[nf], acc[mf][nf], 0, 0, 0);
    }

    float* out = pctx + (size_t)((ch * 4 + w) * 8 + h) * 4096;
    #pragma unroll
    for (int mf = 0; mf < 4; ++mf)
        #pragma unroll
        for (int nf = 0; nf < 4; ++nf)
            #pragma unroll
            for (int r = 0; r < 4; ++r)
                out[(mf * 16 + fq * 4 + r) * 64 + nf * 16 + fr] = acc[mf][nf][r];
}
__global__ void context_reduce_k(const float* __restrict__ pctx, float* __restrict__ ctx) {
    int idx = blockIdx.x * 256 + threadIdx.x;   // 8*4096 = 32768
    int h = idx >> 12, e = idx & 4095;
    float s = 0.f;
    for (int p = 0; p < 128; ++p) s += pctx[(size_t)(p * 8 + h) * 4096 + e];
    ctx[idx] = s;
}

// ---------------- Mt[o][h*64+k] = sum_j ctx[h][k][j] * Wr[h*64+j][o]  (bf16) ----------------
__global__ void mt_k(const float* __restrict__ ctx, const float* __restrict__ Wr,
                     unsigned short* __restrict__ Mt) {
    int idx = blockIdx.x * 256 + threadIdx.x;   // 512*512
    int o = idx >> 9, hk = idx & 511;
    int h = hk >> 6, k = hk & 63;
    float s = 0.f;
    for (int j = 0; j < 64; ++j)
        s += ctx[h * 4096 + k * 64 + j] * Wr[(size_t)(h * 64 + j) * 512 + o];
    Mt[(size_t)o * 512 + hk] = f2bf(s);
}

// ---------------- launch ----------------
extern "C" void kernel_launch(void* const* d_in, const int* in_sizes, int n_in,
                              void* d_out, int out_size, void* d_ws, size_t ws_size,
                              hipStream_t stream) {
    const float* input = (const float*)d_in[0];
    const float* Wk = (const float*)d_in[1];
    const float* bk = (const float*)d_in[2];
    const float* Wq = (const float*)d_in[3];
    const float* bq = (const float*)d_in[4];
    const float* Wv = (const float*)d_in[5];
    const float* bv = (const float*)d_in[6];
    const float* Wr = (const float*)d_in[7];
    const float* br = (const float*)d_in[8];

    char* ws = (char*)d_ws;
    unsigned short* inp_bf = (unsigned short*)ws;  ws += (size_t)NT * CD * 2;
    unsigned short* Wt     = (unsigned short*)ws;  ws += (size_t)1536 * 512 * 2;
    float* biaskqv         = (float*)ws;           ws += 1536 * 4;
    float* KQV             = (float*)ws;           ws += (size_t)NT * KQV_LD * 4;
    float* pmax            = (float*)ws;           ws += 64 * 512 * 4;
    float* cmax            = (float*)ws;           ws += 512 * 4;
    float* psum            = (float*)ws;           ws += 64 * 512 * 4;
    float* crcp            = (float*)ws;           ws += 512 * 4;
    unsigned short* ksm    = (unsigned short*)ws;  ws += (size_t)NT * CD * 2;
    unsigned short* qsm    = (unsigned short*)ws;  ws += (size_t)NT * CD * 2;
    unsigned short* vbf    = (unsigned short*)ws;  ws += (size_t)NT * CD * 2;
    float* ctx             = (float*)ws;           ws += (size_t)8 * 4096 * 4;
    unsigned short* Mt     = (unsigned short*)ws;  ws += (size_t)512 * 512 * 2;
    // pctx (16.8 MB) aliases KQV (50.3 MB): KQV is dead once ksm/qsm/vbf exist.
    float* pctx = KQV;

    float* attn_out   = (float*)d_out;
    float* scores_out = (float*)d_out + (size_t)NT * CD;

    cvt_input_k<<<4096, 256, 0, stream>>>((const float4*)input, inp_bf);
    prep_w_k<<<3072, 256, 0, stream>>>(Wk, Wq, Wv, bk, bq, bv, Wt, biaskqv);

    gemm_bt<<<dim3(12, 64), 256, 0, stream>>>(inp_bf, Wt, KQV, biaskqv, NT, KQV_LD, CD, 1.0f);

    colms_partial_k<<<64, 512, 0, stream>>>(KQV, pmax, psum);
    colms_final_k<<<2, 256, 0, stream>>>(pmax, psum, cmax, crcp);
    ksm_k<<<16384, 256, 0, stream>>>(KQV, cmax, crcp, ksm);
    qsm_v_k<<<16384, 256, 0, stream>>>(KQV, qsm, vbf);

    context_partial_k<<<dim3(32, 8), 256, 0, stream>>>(ksm, vbf, pctx);
    context_reduce_k<<<128, 256, 0, stream>>>(pctx, ctx);
    mt_k<<<1024, 256, 0, stream>>>(ctx, Wr, Mt);

    gemm_bt<<<dim3(4, 64), 256, 0, stream>>>(qsm, Mt, attn_out, br, NT, CD, CD, 1.0f);
    scores_gemm_k<<<1024, 512, 0, stream>>>(qsm, ksm, scores_out);
}